// Round 9
// baseline (2338.253 us; speedup 1.0000x reference)
//
#include <hip/hip_runtime.h>
#include <hip/hip_fp16.h>
#include <hip/hip_cooperative_groups.h>

namespace cg = cooperative_groups;

#define NLAYERS 5

struct alignas(8) H4 { __half h[4]; };

typedef _Float16 f16x8 __attribute__((ext_vector_type(8)));
typedef _Float16 f16x4 __attribute__((ext_vector_type(4)));
typedef float f32x4v __attribute__((ext_vector_type(4)));
typedef unsigned int u32x2 __attribute__((ext_vector_type(2)));

// 4x4 micro-tile GEMM; AT transposed in LDS (given stride), W row-major in LDS.
template <int STRIDE>
__device__ __forceinline__ void gemm_tile(const float* AT, const float* W, float acc[4][4], int ty, int tx) {
    #pragma unroll
    for (int i = 0; i < 4; i++)
        #pragma unroll
        for (int j = 0; j < 4; j++) acc[i][j] = 0.f;
    #pragma unroll 4
    for (int k = 0; k < 64; k++) {
        const float4 a4 = *(const float4*)(AT + k * STRIDE + ty * 4);
        const float4 b4 = *(const float4*)(W + k * 64 + tx * 4);
        float a[4] = {a4.x, a4.y, a4.z, a4.w};
        float b[4] = {b4.x, b4.y, b4.z, b4.w};
        #pragma unroll
        for (int i = 0; i < 4; i++)
            #pragma unroll
            for (int j = 0; j < 4; j++) acc[i][j] += a[i] * b[j];
    }
}

// packed xW1 index: channel c -> p = (c&15)*4 + (c>>4)
__device__ __forceinline__ int xw1_pack(int c) { return ((c & 15) << 2) | (c >> 4); }

// Persistent cooperative mega-kernel: all setup + the 5-layer edge/node loop.
// Phases separated by device-fenced grid syncs (agent-scope fence = L2 wb/inv,
// same coherence work a kernel boundary does; saves the dispatch ramp/drain).
__global__ __launch_bounds__(256, 4) void k_mega(
        const float* __restrict__ X, const int* __restrict__ ei,
        const float* __restrict__ edge_attr, const int* __restrict__ batch,
        const float* nn2_w1, const float* nn2_b1, const float* nn2_w2, const float* nn2_b2,
        const float* nn1_w1, const float* nn1_b1, const float* nn1_w2, const float* nn1_b2,
        const float* epsp,
        int* deg, int* rank, int* cnt, int* cursor, int* rowptr,
        int* csr_src, int* csr_eid,
        __half* eaH, __half* eaC,
        __half* Ff, float* pb, float* qb, float* rb, __half* Bfrag,
        __half* xW1p, __half* xA0p, __half* xA1p, __half* Hsum16,
        float* hpool, int N, int E, int G) {
    __shared__ union ShMem {
        struct { float XT[64 * 68]; float W[64 * 64]; } prep;
        struct { _Float16 hL[64 * 72]; float shp[8 * 64]; } node;
        int scan[256];
    } S;
    __shared__ int obase;
    cg::grid_group grid = cg::this_grid();

    int t = threadIdx.x;
    int wave = t >> 6, lane = t & 63;
    int quad = lane >> 4, nn = lane & 15;
    float eps1 = 1.f + epsp[0];
    int nb64 = (N + 63) / 64;

    // ---------------- phase A: prep jobs + rank/convert ----------------
    for (int job = blockIdx.x; job < 18 + nb64; job += gridDim.x) {
        if (job >= 13 && job < 18) {
            int l = job - 13;
            const float* We = nn2_w1 + (size_t)l * 5120 + 64 * 64;  // [16][64]
            for (int idx = t; idx < 2048; idx += 256) {
                int tt = idx >> 9;
                int ln = (idx >> 3) & 63;
                int j = idx & 7;
                int k = (ln >> 4) * 8 + j;
                int n = ln & 15;
                float v = (k < 16) ? We[k * 64 + tt * 16 + n] : 0.f;
                Bfrag[((size_t)(l * 4 + tt) * 64 + ln) * 8 + j] = __float2half(v);
            }
        } else if (job < 13) {
            const float* left; const float* lb; const float* right; float* ob;
            float scl = 1.f; const float* badd = nullptr;
            if (job < 5) {
                int l = job;
                left = nn2_w2 + l * 4096; lb = nn2_b2 + l * 64; right = nn1_w1 + l * 4096;
                ob = pb + l * 64;
            } else if (job < 9) {
                int l = job - 5;
                left = nn1_w2 + l * 4096; lb = nn1_b2 + l * 64; right = nn2_w1 + (l + 1) * 5120;
                ob = qb + l * 64; badd = nn2_b1 + (l + 1) * 64;
            } else {
                int l = job - 9;
                left = nn1_w2 + l * 4096; lb = nn1_b2 + l * 64; right = nn1_w1 + (l + 1) * 4096;
                ob = rb + l * 64; scl = eps1; badd = nn1_b1 + (l + 1) * 64;
            }
            __half* out = Ff + (size_t)job * 4096;
            int r0 = (t >> 4) * 4, c0 = (t & 15) * 4;
            float acc[4][4] = {};
            for (int k = 0; k < 64; k++) {
                float b[4];
                #pragma unroll
                for (int j = 0; j < 4; j++) b[j] = right[k * 64 + c0 + j];
                #pragma unroll
                for (int i = 0; i < 4; i++) {
                    float a = left[(r0 + i) * 64 + k];
                    #pragma unroll
                    for (int j = 0; j < 4; j++) acc[i][j] += a * b[j];
                }
            }
            for (int i = 0; i < 4; i++) {
                int k = r0 + i;
                int kh = k >> 5, q = (k & 31) >> 3, jj = k & 7;
                for (int j = 0; j < 4; j++) {
                    int c = c0 + j;
                    int nt = c >> 4, cn = c & 15;
                    out[((size_t)(nt * 2 + kh) * 64 + q * 16 + cn) * 8 + jj] = __float2half(scl * acc[i][j]);
                }
            }
            if (t < 64) {
                float s = 0.f;
                for (int k = 0; k < 64; k++) s += lb[k] * right[k * 64 + t];
                s *= scl;
                if (badd) s += badd[t];
                ob[t] = s;
            }
        } else {
            // layer-0 node GEMMs
            int ty = t >> 4, tx = t & 15;
            int base = (job - 18) * 64;
            for (int q = 0; q < 4; q++) {
                int row = ty + q * 16;
                int gr = base + row;
                float4 v = make_float4(0.f, 0.f, 0.f, 0.f);
                if (gr < N) v = *(const float4*)(X + (size_t)gr * 64 + tx * 4);
                S.prep.XT[(tx * 4 + 0) * 68 + row] = v.x;
                S.prep.XT[(tx * 4 + 1) * 68 + row] = v.y;
                S.prep.XT[(tx * 4 + 2) * 68 + row] = v.z;
                S.prep.XT[(tx * 4 + 3) * 68 + row] = v.w;
            }
            for (int q = 0; q < 4; q++) ((float4*)S.prep.W)[t + q * 256] = ((const float4*)nn2_w1)[t + q * 256];
            __syncthreads();
            float acc[4][4];
            gemm_tile<68>(S.prep.XT, S.prep.W, acc, ty, tx);
            for (int i = 0; i < 4; i++) {
                int gr = base + ty * 4 + i;
                if (gr < N) {
                    #pragma unroll
                    for (int j = 0; j < 4; j++) {
                        int c = tx * 4 + j;
                        xW1p[(size_t)gr * 64 + xw1_pack(c)] = __float2half(acc[i][j] + nn2_b1[c]);
                    }
                }
            }
            __syncthreads();
            for (int q = 0; q < 4; q++) ((float4*)S.prep.W)[t + q * 256] = ((const float4*)nn1_w1)[t + q * 256];
            __syncthreads();
            gemm_tile<68>(S.prep.XT, S.prep.W, acc, ty, tx);
            for (int i = 0; i < 4; i++) {
                int gr = base + ty * 4 + i;
                if (gr < N) {
                    #pragma unroll
                    for (int j = 0; j < 4; j++) {
                        int c = tx * 4 + j;
                        xA0p[(size_t)gr * 64 + xw1_pack(c)] = __float2half(eps1 * acc[i][j] + nn1_b1[c]);
                    }
                }
            }
        }
        __syncthreads();
    }
    // rank + deg histogram + cnt histogram + eaH convert (coalesced)
    for (int i0 = blockIdx.x * 256; i0 < E; i0 += gridDim.x * 256) {
        int i = i0 + t;
        if (i < E) {
            int s = ei[i], d = ei[E + i];
            rank[i] = (s != d) ? atomicAdd(&deg[d], 1) : -1;
            const f32x4v* ea4 = (const f32x4v*)(edge_attr + (size_t)i * 16);
            f32x4v a = __builtin_nontemporal_load(ea4);
            f32x4v b = __builtin_nontemporal_load(ea4 + 1);
            f32x4v c = __builtin_nontemporal_load(ea4 + 2);
            f32x4v dd = __builtin_nontemporal_load(ea4 + 3);
            union { _Float16 h[8]; f32x4v f; } u0, u1;
            #pragma unroll
            for (int q = 0; q < 4; q++) { u0.h[q] = (_Float16)a[q]; u0.h[4 + q] = (_Float16)b[q]; }
            #pragma unroll
            for (int q = 0; q < 4; q++) { u1.h[q] = (_Float16)c[q]; u1.h[4 + q] = (_Float16)dd[q]; }
            f32x4v* out = (f32x4v*)(eaH + (size_t)i * 16);
            out[0] = u0.f;
            out[1] = u1.f;
        }
        bool valid = (i < N);
        int b = valid ? batch[i] : -1;
        int prevb = __shfl_up(b, 1);
        bool leader = valid && ((lane == 0) || (prevb != b));
        unsigned long long lm = __ballot(leader);
        unsigned long long am = __ballot(valid);
        if (leader) {
            unsigned long long above = (lane < 63) ? (lm >> (lane + 1)) : 0ULL;
            int next = above ? (lane + 1 + (__ffsll((long long)above) - 1)) : 64;
            int nact = __popcll(am);
            if (next > nact) next = nact;
            atomicAdd(&cnt[b], next - lane);
        }
    }
    __threadfence(); grid.sync(); __threadfence();

    // ---------------- phase B: segment-base assignment ----------------
    int Pblk = (N + 255) / 256;
    for (int tile = blockIdx.x; tile < Pblk; tile += gridDim.x) {
        int i = tile * 256 + t;
        int v = (i < N) ? deg[i] : 0;
        S.scan[t] = v;
        __syncthreads();
        for (int o = 1; o < 256; o <<= 1) {
            int u = (t >= o) ? S.scan[t - o] : 0;
            __syncthreads();
            S.scan[t] += u;
            __syncthreads();
        }
        if (t == 255) obase = atomicAdd(cursor, S.scan[255]);
        __syncthreads();
        if (i < N) rowptr[i] = obase + S.scan[t] - v;
        __syncthreads();
    }
    __threadfence(); grid.sync(); __threadfence();

    // ---------------- phase C: scatter small indices ----------------
    for (int e0 = blockIdx.x * 256; e0 < E; e0 += gridDim.x * 256) {
        int e = e0 + t;
        if (e < E) {
            int r = rank[e];
            if (r >= 0) {
                int j = rowptr[ei[E + e]] + r;
                csr_src[j] = ei[e];
                csr_eid[j] = e;
            }
        }
    }
    __threadfence(); grid.sync(); __threadfence();

    // ---------------- layer loop ----------------
    int gw = blockIdx.x * 4 + wave;
    int gws = gridDim.x * 4;
    const f32x4v zero = {0.f, 0.f, 0.f, 0.f};
    for (int l = 0; l < NLAYERS; l++) {
        // ---- edge phase: one wave per node, persistent stride ----
        {
            const __half* BfL = Bfrag + (size_t)l * 2048;
            f16x8 Bf[4];
            #pragma unroll
            for (int tt = 0; tt < 4; tt++)
                Bf[tt] = *(const f16x8*)(BfL + ((size_t)tt * 64 + lane) * 8);
            bool l0 = (l == 0);
            for (int wid = gw; wid < N; wid += gws) {
                int beg = __builtin_amdgcn_readfirstlane(rowptr[wid]);
                int end = beg + __builtin_amdgcn_readfirstlane(deg[wid]);
                float acc[4] = {0.f, 0.f, 0.f, 0.f};
                for (int cbeg = beg; cbeg < end; cbeg += 16) {
                    int m = end - cbeg; m = (m < 16) ? m : 16;
                    int xs[4];
                    #pragma unroll
                    for (int r = 0; r < 4; r++) {
                        int slot = cbeg + quad * 4 + r;
                        slot = (slot < end) ? slot : (end - 1);
                        xs[r] = csr_src[slot];
                    }
                    f16x8 Af;
                    #pragma unroll
                    for (int j = 0; j < 8; j++) Af[j] = (_Float16)0;
                    if (quad < 2) {
                        int slot = cbeg + ((nn < m) ? nn : 0);
                        if (l0) {
                            int eid = csr_eid[slot];
                            f16x8 av = *(const f16x8*)(eaH + (size_t)eid * 16 + quad * 8);
                            if (nn < m) {
                                Af = av;
                                *(f16x8*)(eaC + (size_t)(cbeg + nn) * 16 + quad * 8) = av;
                            }
                        } else {
                            f16x8 av = *(const f16x8*)(eaC + (size_t)slot * 16 + quad * 8);
                            if (nn < m) Af = av;
                        }
                    }
                    u32x2 xv[4];
                    #pragma unroll
                    for (int r = 0; r < 4; r++)
                        xv[r] = *(const u32x2*)(xW1p + (size_t)xs[r] * 64 + nn * 4);
                    if (m == 16) {
                        #pragma unroll
                        for (int tt = 0; tt < 4; tt++) {
                            f32x4v D = __builtin_amdgcn_mfma_f32_16x16x32_f16(Af, Bf[tt], zero, 0, 0, 0);
                            #pragma unroll
                            for (int r = 0; r < 4; r++) {
                                f16x4 xh = __builtin_bit_cast(f16x4, xv[r]);
                                acc[tt] += fmaxf(D[r] + (float)xh[tt], 0.f);
                            }
                        }
                    } else {
                        #pragma unroll
                        for (int tt = 0; tt < 4; tt++) {
                            f32x4v D = __builtin_amdgcn_mfma_f32_16x16x32_f16(Af, Bf[tt], zero, 0, 0, 0);
                            #pragma unroll
                            for (int r = 0; r < 4; r++) {
                                int e = quad * 4 + r;
                                f16x4 xh = __builtin_bit_cast(f16x4, xv[r]);
                                float z = fmaxf(D[r] + (float)xh[tt], 0.f);
                                acc[tt] += (e < m) ? z : 0.f;
                            }
                        }
                    }
                }
                #pragma unroll
                for (int tt = 0; tt < 4; tt++) {
                    acc[tt] += __shfl_xor(acc[tt], 16);
                    acc[tt] += __shfl_xor(acc[tt], 32);
                }
                if (quad == 0) {
                    #pragma unroll
                    for (int tt = 0; tt < 4; tt++)
                        Hsum16[(size_t)wid * 64 + tt * 16 + nn] = __float2half(acc[tt]);
                }
            }
        }
        __threadfence(); grid.sync(); __threadfence();

        // ---- node phase: 64 nodes per block per iter ----
        {
            int has_next = (l < NLAYERS - 1) ? 1 : 0;
            int lq = has_next ? l : 0;
            const __half* Pf = Ff + (size_t)l * 4096;
            const __half* Qf = Ff + (size_t)(5 + lq) * 4096;
            const __half* Rf = Ff + (size_t)(9 + lq) * 4096;
            const float* pbL = pb + l * 64;
            const float* qbL = qb + lq * 64;
            const float* rbL = rb + lq * 64;
            const __half* xAcur = (l & 1) ? xA1p : xA0p;
            __half* xAnxt = (l & 1) ? xA0p : xA1p;
            float* hpool_l = hpool + (size_t)l * (size_t)G * 64;
            int n = nn;
            for (int base = blockIdx.x * 64; base < N; base += gridDim.x * 64) {
                int m0 = base + wave * 16;
                int lastn = base + 63; if (lastn > N - 1) lastn = N - 1;
                int gmin = batch[base];
                int span = batch[lastn] - gmin + 1;
                if (span <= 8) {
                    for (int q = t; q < span * 64; q += 256) S.node.shp[q] = 0.f;
                }
                __syncthreads();

                int arow = m0 + n; if (arow > N - 1) arow = N - 1;
                f16x8 A0 = *(const f16x8*)(Hsum16 + (size_t)arow * 64 + quad * 8);
                f16x8 A1 = *(const f16x8*)(Hsum16 + (size_t)arow * 64 + 32 + quad * 8);

                f32x4v D[4];
                #pragma unroll
                for (int nt = 0; nt < 4; nt++) {
                    f16x8 B0 = *(const f16x8*)(Pf + ((size_t)(nt * 2 + 0) * 64 + lane) * 8);
                    f16x8 B1 = *(const f16x8*)(Pf + ((size_t)(nt * 2 + 1) * 64 + lane) * 8);
                    f32x4v c0 = {0.f, 0.f, 0.f, 0.f};
                    c0 = __builtin_amdgcn_mfma_f32_16x16x32_f16(A0, B0, c0, 0, 0, 0);
                    D[nt] = __builtin_amdgcn_mfma_f32_16x16x32_f16(A1, B1, c0, 0, 0, 0);
                }

                float pbv[4];
                #pragma unroll
                for (int nt = 0; nt < 4; nt++) pbv[nt] = pbL[nt * 16 + n];

                float h[4][4];
                int gidx[4];
                #pragma unroll
                for (int r = 0; r < 4; r++) {
                    int node = m0 + quad * 4 + r;
                    int nc = (node < N) ? node : (N - 1);
                    float dg = 0.f; int g = -1;
                    if (node < N) {
                        dg = (float)deg[node];
                        g = batch[node];
                    }
                    gidx[r] = g;
                    u32x2 xv = *(const u32x2*)(xAcur + (size_t)nc * 64 + n * 4);
                    f16x4 xh = __builtin_bit_cast(f16x4, xv);
                    #pragma unroll
                    for (int nt = 0; nt < 4; nt++)
                        h[r][nt] = fmaxf(D[nt][r] + (float)xh[nt] + dg * pbv[nt], 0.f);
                }

                if (span <= 8) {
                    #pragma unroll
                    for (int nt = 0; nt < 4; nt++) {
                        int i = 0;
                        while (i < 4) {
                            if (gidx[i] < 0) { i++; continue; }
                            int g = gidx[i];
                            float s = h[i][nt];
                            int k2 = i + 1;
                            while (k2 < 4 && gidx[k2] == g) { s += h[k2][nt]; k2++; }
                            atomicAdd(&S.node.shp[(g - gmin) * 64 + nt * 16 + n], s);
                            i = k2;
                        }
                    }
                    __syncthreads();
                    for (int q = t; q < span * 64; q += 256) {
                        float v = S.node.shp[q];
                        if (v != 0.f) atomicAdd(&hpool_l[(gmin + (q >> 6)) * 64 + (q & 63)], v);
                    }
                } else {
                    #pragma unroll
                    for (int nt = 0; nt < 4; nt++) {
                        int i = 0;
                        while (i < 4) {
                            if (gidx[i] < 0) { i++; continue; }
                            int g = gidx[i];
                            float s = h[i][nt];
                            int k2 = i + 1;
                            while (k2 < 4 && gidx[k2] == g) { s += h[k2][nt]; k2++; }
                            atomicAdd(&hpool_l[g * 64 + nt * 16 + n], s);
                            i = k2;
                        }
                    }
                }

                if (has_next) {
                    #pragma unroll
                    for (int r = 0; r < 4; r++) {
                        int lrow = wave * 16 + quad * 4 + r;
                        #pragma unroll
                        for (int nt = 0; nt < 4; nt++)
                            S.node.hL[lrow * 72 + nt * 16 + n] = (_Float16)h[r][nt];
                    }
                    // no barrier: wave reads only rows it wrote
                    int lrowA = wave * 16 + n;
                    f16x8 hA0 = *(const f16x8*)(S.node.hL + lrowA * 72 + quad * 8);
                    f16x8 hA1 = *(const f16x8*)(S.node.hL + lrowA * 72 + 32 + quad * 8);
                    f32x4v D2[4];
                    #pragma unroll
                    for (int nt = 0; nt < 4; nt++) {
                        f16x8 B0 = *(const f16x8*)(Qf + ((size_t)(nt * 2 + 0) * 64 + lane) * 8);
                        f16x8 B1 = *(const f16x8*)(Qf + ((size_t)(nt * 2 + 1) * 64 + lane) * 8);
                        f32x4v c0 = {0.f, 0.f, 0.f, 0.f};
                        c0 = __builtin_amdgcn_mfma_f32_16x16x32_f16(hA0, B0, c0, 0, 0, 0);
                        D2[nt] = __builtin_amdgcn_mfma_f32_16x16x32_f16(hA1, B1, c0, 0, 0, 0);
                    }
                    float qbv[4];
                    #pragma unroll
                    for (int nt = 0; nt < 4; nt++) qbv[nt] = qbL[nt * 16 + n];
                    #pragma unroll
                    for (int r = 0; r < 4; r++) {
                        int node = m0 + quad * 4 + r;
                        if (node < N) {
                            H4 o;
                            #pragma unroll
                            for (int nt = 0; nt < 4; nt++) o.h[nt] = __float2half(D2[nt][r] + qbv[nt]);
                            *(H4*)(xW1p + (size_t)node * 64 + n * 4) = o;
                        }
                    }
                    #pragma unroll
                    for (int nt = 0; nt < 4; nt++) {
                        f16x8 B0 = *(const f16x8*)(Rf + ((size_t)(nt * 2 + 0) * 64 + lane) * 8);
                        f16x8 B1 = *(const f16x8*)(Rf + ((size_t)(nt * 2 + 1) * 64 + lane) * 8);
                        f32x4v c0 = {0.f, 0.f, 0.f, 0.f};
                        c0 = __builtin_amdgcn_mfma_f32_16x16x32_f16(hA0, B0, c0, 0, 0, 0);
                        D2[nt] = __builtin_amdgcn_mfma_f32_16x16x32_f16(hA1, B1, c0, 0, 0, 0);
                    }
                    float rbv[4];
                    #pragma unroll
                    for (int nt = 0; nt < 4; nt++) rbv[nt] = rbL[nt * 16 + n];
                    #pragma unroll
                    for (int r = 0; r < 4; r++) {
                        int node = m0 + quad * 4 + r;
                        if (node < N) {
                            f16x4 o;
                            #pragma unroll
                            for (int nt = 0; nt < 4; nt++) o[nt] = (_Float16)(D2[nt][r] + rbv[nt]);
                            *(f16x4*)(xAnxt + (size_t)node * 64 + n * 4) = o;
                        }
                    }
                }
                __syncthreads();
            }
        }
        if (l < NLAYERS - 1) { __threadfence(); grid.sync(); __threadfence(); }
    }
}

// fused readout: 4 groups per block amortizes the F1 stream.
#define GPB 4
__global__ void k_pool_final(const float* __restrict__ hpool, const int* __restrict__ cnt,
                             const float* __restrict__ nn1_w2, const float* __restrict__ nn1_b2,
                             const float* __restrict__ F1, const float* __restrict__ fb1,
                             const float* __restrict__ F2, const float* __restrict__ fb2,
                             float* __restrict__ out, int G) {
    int g0 = blockIdx.x * GPB;
    int c = threadIdx.x; // 320
    int lane = c & 63, w = c >> 6;
    int l = c >> 6, cc = c & 63;
    const float* B = nn1_w2 + l * 4096;
    __shared__ float sh1[GPB][320];
    __shared__ float ws[GPB][8];
    float bias = nn1_b2[l * 64 + cc];
    #pragma unroll
    for (int gi = 0; gi < GPB; gi++) {
        int g = g0 + gi;
        if (g >= G) break;
        const float* hp = hpool + ((size_t)l * G + g) * 64;
        float s = (float)cnt[g] * bias;
        for (int k = 0; k < 64; k++) s += hp[k] * B[k * 64 + cc];
        sh1[gi][c] = s;
    }
    __syncthreads();
    float acc[GPB];
    #pragma unroll
    for (int gi = 0; gi < GPB; gi++) acc[gi] = fb1[c];
    for (int k = 0; k < 320; k++) {
        float wv = F1[k * 320 + c];
        #pragma unroll
        for (int gi = 0; gi < GPB; gi++) acc[gi] += sh1[gi][k] * wv;
    }
    float f2 = F2[c];
    #pragma unroll
    for (int gi = 0; gi < GPB; gi++) {
        float v = fmaxf(acc[gi], 0.f) * f2;
        v += __shfl_xor(v, 32);
        v += __shfl_xor(v, 16);
        v += __shfl_xor(v, 8);
        v += __shfl_xor(v, 4);
        v += __shfl_xor(v, 2);
        v += __shfl_xor(v, 1);
        if (lane == 0) ws[gi][w] = v;
    }
    __syncthreads();
    if (c < GPB) {
        int g = g0 + c;
        if (g < G) {
            float y = fb2[0];
            #pragma unroll
            for (int k = 0; k < 5; k++) y += ws[c][k];
            out[g] = y;
        }
    }
}

extern "C" void kernel_launch(void* const* d_in, const int* in_sizes, int n_in,
                              void* d_out, int out_size, void* d_ws, size_t ws_size,
                              hipStream_t stream) {
    const float* x        = (const float*)d_in[0];
    const int*   ei       = (const int*)d_in[1];
    const float* edge_attr= (const float*)d_in[2];
    const int*   batch    = (const int*)d_in[3];
    const float* nn2_w1   = (const float*)d_in[4];
    const float* nn2_b1   = (const float*)d_in[5];
    const float* nn2_w2   = (const float*)d_in[6];
    const float* nn2_b2   = (const float*)d_in[7];
    const float* nn1_w1   = (const float*)d_in[8];
    const float* nn1_b1   = (const float*)d_in[9];
    const float* nn1_w2   = (const float*)d_in[10];
    const float* nn1_b2   = (const float*)d_in[11];
    const float* fin_w1   = (const float*)d_in[12];
    const float* fin_b1   = (const float*)d_in[13];
    const float* fin_w2   = (const float*)d_in[14];
    const float* fin_b2   = (const float*)d_in[15];
    const float* eps      = (const float*)d_in[16];

    int N = in_sizes[0] / 64;
    int E = in_sizes[1] / 2;
    int G = out_size;

    char* p = (char*)d_ws;
    auto alloc = [&](size_t bytes) -> char* {
        char* r = p;
        p += (bytes + 255) & ~(size_t)255;
        return r;
    };
    // zero-init region: deg, cnt, cursor, hpool — contiguous, one memset.
    char*   zbase   = p;
    int*    deg     = (int*)alloc((size_t)N * 4);
    int*    cnt     = (int*)alloc((size_t)G * 4);
    int*    cursor  = (int*)alloc(256);
    float*  hpool   = (float*)alloc((size_t)NLAYERS * G * 64 * 4);
    size_t  zlen    = (size_t)(p - zbase);

    int*    rowptr  = (int*)alloc((size_t)N * 4);
    int*    rank    = (int*)alloc((size_t)E * 4);
    int*    csr_src = (int*)alloc((size_t)E * 4 + 256);
    int*    csr_eid = (int*)alloc((size_t)E * 4 + 256);
    __half* eaH     = (__half*)alloc((size_t)E * 16 * 2 + 1024);
    __half* eaC     = (__half*)alloc((size_t)E * 16 * 2 + 1024);
    __half* xW1p    = (__half*)alloc((size_t)N * 64 * 2);
    __half* xA0p    = (__half*)alloc((size_t)N * 64 * 2);
    __half* xA1p    = (__half*)alloc((size_t)N * 64 * 2);
    __half* Hsum16  = (__half*)alloc((size_t)N * 64 * 2);
    __half* Ff      = (__half*)alloc(13 * 4096 * 2);
    float*  pb      = (float*)alloc(5 * 64 * 4);
    float*  qb      = (float*)alloc(4 * 64 * 4);
    float*  rb      = (float*)alloc(4 * 64 * 4);
    __half* Bfrag   = (__half*)alloc(5 * 4 * 64 * 8 * 2);

    hipMemsetAsync(zbase, 0, zlen, stream);

    // cooperative grid sizing (cached; host-side query, graph-capture-safe)
    static int megaGrid = 0;
    if (megaGrid == 0) {
        int mb = 0;
        hipError_t err = hipOccupancyMaxActiveBlocksPerMultiprocessor(&mb, k_mega, 256, 0);
        if (err != hipSuccess || mb < 1) mb = 2;
        if (mb > 4) mb = 4;
        megaGrid = mb * 256;
    }

    void* args[] = {
        (void*)&x, (void*)&ei, (void*)&edge_attr, (void*)&batch,
        (void*)&nn2_w1, (void*)&nn2_b1, (void*)&nn2_w2, (void*)&nn2_b2,
        (void*)&nn1_w1, (void*)&nn1_b1, (void*)&nn1_w2, (void*)&nn1_b2,
        (void*)&eps,
        (void*)&deg, (void*)&rank, (void*)&cnt, (void*)&cursor, (void*)&rowptr,
        (void*)&csr_src, (void*)&csr_eid,
        (void*)&eaH, (void*)&eaC,
        (void*)&Ff, (void*)&pb, (void*)&qb, (void*)&rb, (void*)&Bfrag,
        (void*)&xW1p, (void*)&xA0p, (void*)&xA1p, (void*)&Hsum16,
        (void*)&hpool, (void*)&N, (void*)&E, (void*)&G
    };
    hipLaunchCooperativeKernel((void*)k_mega, dim3(megaGrid), dim3(256), args, 0, stream);

    k_pool_final<<<(G + GPB - 1) / GPB, 320, 0, stream>>>(hpool, cnt, nn1_w2, nn1_b2,
                                        fin_w1, fin_b1, fin_w2, fin_b2, (float*)d_out, G);
}

// Round 10
// 451.815 us; speedup vs baseline: 5.1752x; 5.1752x over previous
//
#include <hip/hip_runtime.h>
#include <hip/hip_fp16.h>

#define NLAYERS 5

struct alignas(8) H4 { __half h[4]; };

typedef _Float16 f16x8 __attribute__((ext_vector_type(8)));
typedef _Float16 f16x4 __attribute__((ext_vector_type(4)));
typedef float f32x4v __attribute__((ext_vector_type(4)));
typedef unsigned int u32x2 __attribute__((ext_vector_type(2)));

// ---------------- setup kernels ----------------
// one thread per edge: deg histogram + rank + coalesced f16 convert of edge_attr
// (eaH, eid-indexed). NT loads (stream past L2) but REGULAR stores (L2 merges
// adjacent 32B records into full lines; NT stores cost 2x write amplification).
__global__ void k_rank(const int* __restrict__ ei, int E, int* __restrict__ deg,
                       int* __restrict__ rank, const int* __restrict__ batch, int N,
                       int* __restrict__ cnt,
                       const float* __restrict__ edge_attr, __half* __restrict__ eaH) {
    int t = threadIdx.x;
    int i = blockIdx.x * 256 + t;
    int lane = t & 63;
    if (i < E) {
        int s = ei[i], d = ei[E + i];
        rank[i] = (s != d) ? atomicAdd(&deg[d], 1) : -1;
        const f32x4v* ea4 = (const f32x4v*)(edge_attr + (size_t)i * 16);
        f32x4v a = __builtin_nontemporal_load(ea4);
        f32x4v b = __builtin_nontemporal_load(ea4 + 1);
        f32x4v c = __builtin_nontemporal_load(ea4 + 2);
        f32x4v dd = __builtin_nontemporal_load(ea4 + 3);
        union { _Float16 h[8]; f32x4v f; } u0, u1;
        #pragma unroll
        for (int q = 0; q < 4; q++) { u0.h[q] = (_Float16)a[q]; u0.h[4 + q] = (_Float16)b[q]; }
        #pragma unroll
        for (int q = 0; q < 4; q++) { u1.h[q] = (_Float16)c[q]; u1.h[4 + q] = (_Float16)dd[q]; }
        f32x4v* out = (f32x4v*)(eaH + (size_t)i * 16);
        out[0] = u0.f;
        out[1] = u1.f;
    }
    bool valid = (i < N);
    int b = valid ? batch[i] : -1;
    int prevb = __shfl_up(b, 1);
    bool leader = valid && ((lane == 0) || (prevb != b));
    unsigned long long lm = __ballot(leader);
    unsigned long long am = __ballot(valid);
    if (leader) {
        unsigned long long above = (lane < 63) ? (lm >> (lane + 1)) : 0ULL;
        int next = above ? (lane + 1 + (__ffsll((long long)above) - 1)) : 64;
        int nact = __popcll(am);
        if (next > nact) next = nact;
        atomicAdd(&cnt[b], next - lane);
    }
}

// single-kernel segment-base assignment: block-local scan + atomic cursor.
__global__ void k_off(const int* __restrict__ deg, int N, int* __restrict__ cursor,
                      int* __restrict__ rowptr) {
    __shared__ int sh[256];
    __shared__ int base;
    int t = threadIdx.x, i = blockIdx.x * 256 + t;
    int v = (i < N) ? deg[i] : 0;
    sh[t] = v;
    __syncthreads();
    for (int o = 1; o < 256; o <<= 1) {
        int u = (t >= o) ? sh[t - o] : 0;
        __syncthreads();
        sh[t] += u;
        __syncthreads();
    }
    if (t == 255) base = atomicAdd(cursor, sh[255]);
    __syncthreads();
    if (i < N) rowptr[i] = base + sh[t] - v;
}

// scatter only the small indices (4B each): 64B lines merge in L2.
__global__ void k_scatter_sd(const int* __restrict__ ei, const int* __restrict__ rank,
                             const int* __restrict__ rowptr, int E,
                             int* __restrict__ csr_src, int* __restrict__ csr_eid) {
    int e = blockIdx.x * blockDim.x + threadIdx.x;
    if (e >= E) return;
    int r = rank[e];
    if (r < 0) return;
    int j = rowptr[ei[E + e]] + r;
    csr_src[j] = ei[e];
    csr_eid[j] = e;
}

// 4x4 micro-tile GEMM; AT transposed in LDS (given stride), W row-major in LDS.
template <int STRIDE>
__device__ __forceinline__ void gemm_tile(const float* AT, const float* W, float acc[4][4], int ty, int tx) {
    #pragma unroll
    for (int i = 0; i < 4; i++)
        #pragma unroll
        for (int j = 0; j < 4; j++) acc[i][j] = 0.f;
    #pragma unroll 4
    for (int k = 0; k < 64; k++) {
        const float4 a4 = *(const float4*)(AT + k * STRIDE + ty * 4);
        const float4 b4 = *(const float4*)(W + k * 64 + tx * 4);
        float a[4] = {a4.x, a4.y, a4.z, a4.w};
        float b[4] = {b4.x, b4.y, b4.z, b4.w};
        #pragma unroll
        for (int i = 0; i < 4; i++)
            #pragma unroll
            for (int j = 0; j < 4; j++) acc[i][j] += a[i] * b[j];
    }
}

// packed xW1 index: channel c -> p = (c&15)*4 + (c>>4)
__device__ __forceinline__ int xw1_pack(int c) { return ((c & 15) << 2) | (c >> 4); }

// Standalone prep kernel (see layout comments in earlier rounds).
__global__ void k_prep(const float* __restrict__ X,
                       const float* nn2_w1, const float* nn2_b1,
                       const float* nn2_w2, const float* nn2_b2,
                       const float* nn1_w1, const float* nn1_b1,
                       const float* nn1_w2, const float* nn1_b2,
                       const float* __restrict__ epsp,
                       __half* Ff, float* pb, float* qb, float* rb,
                       __half* Bfrag, __half* __restrict__ xW1p, __half* __restrict__ xA0p,
                       int N) {
    __shared__ float XT[64 * 68];
    __shared__ float W[64 * 64];
    int job = blockIdx.x;
    int t = threadIdx.x;
    float eps1 = 1.f + epsp[0];
    if (job >= 13 && job < 18) {
        int l = job - 13;
        const float* We = nn2_w1 + (size_t)l * 5120 + 64 * 64;  // [16][64]
        for (int idx = t; idx < 2048; idx += 256) {
            int tt = idx >> 9;
            int lane = (idx >> 3) & 63;
            int j = idx & 7;
            int k = (lane >> 4) * 8 + j;
            int n = lane & 15;
            float v = (k < 16) ? We[k * 64 + tt * 16 + n] : 0.f;
            Bfrag[((size_t)(l * 4 + tt) * 64 + lane) * 8 + j] = __float2half(v);
        }
        return;
    }
    if (job < 13) {
        const float* left; const float* lb; const float* right; float* ob;
        float scl = 1.f; const float* badd = nullptr;
        if (job < 5) {
            int l = job;
            left = nn2_w2 + l * 4096; lb = nn2_b2 + l * 64; right = nn1_w1 + l * 4096;
            ob = pb + l * 64;
        } else if (job < 9) {
            int l = job - 5;
            left = nn1_w2 + l * 4096; lb = nn1_b2 + l * 64; right = nn2_w1 + (l + 1) * 5120;
            ob = qb + l * 64; badd = nn2_b1 + (l + 1) * 64;
        } else {
            int l = job - 9;
            left = nn1_w2 + l * 4096; lb = nn1_b2 + l * 64; right = nn1_w1 + (l + 1) * 4096;
            ob = rb + l * 64; scl = eps1; badd = nn1_b1 + (l + 1) * 64;
        }
        __half* out = Ff + (size_t)job * 4096;
        int r0 = (t >> 4) * 4, c0 = (t & 15) * 4;
        float acc[4][4] = {};
        for (int k = 0; k < 64; k++) {
            float b[4];
            #pragma unroll
            for (int j = 0; j < 4; j++) b[j] = right[k * 64 + c0 + j];
            #pragma unroll
            for (int i = 0; i < 4; i++) {
                float a = left[(r0 + i) * 64 + k];
                #pragma unroll
                for (int j = 0; j < 4; j++) acc[i][j] += a * b[j];
            }
        }
        for (int i = 0; i < 4; i++) {
            int k = r0 + i;
            int kh = k >> 5, q = (k & 31) >> 3, jj = k & 7;
            for (int j = 0; j < 4; j++) {
                int c = c0 + j;
                int nt = c >> 4, nn = c & 15;
                out[((size_t)(nt * 2 + kh) * 64 + q * 16 + nn) * 8 + jj] = __float2half(scl * acc[i][j]);
            }
        }
        if (t < 64) {
            float s = 0.f;
            for (int k = 0; k < 64; k++) s += lb[k] * right[k * 64 + t];
            s *= scl;
            if (badd) s += badd[t];
            ob[t] = s;
        }
        return;
    }
    // layer-0 node GEMMs
    int ty = t >> 4, tx = t & 15;
    int base = (job - 18) * 64;
    for (int q = 0; q < 4; q++) {
        int row = ty + q * 16;
        int gr = base + row;
        float4 v = make_float4(0.f, 0.f, 0.f, 0.f);
        if (gr < N) v = *(const float4*)(X + (size_t)gr * 64 + tx * 4);
        XT[(tx * 4 + 0) * 68 + row] = v.x;
        XT[(tx * 4 + 1) * 68 + row] = v.y;
        XT[(tx * 4 + 2) * 68 + row] = v.z;
        XT[(tx * 4 + 3) * 68 + row] = v.w;
    }
    for (int q = 0; q < 4; q++) ((float4*)W)[t + q * 256] = ((const float4*)nn2_w1)[t + q * 256];
    __syncthreads();
    float acc[4][4];
    gemm_tile<68>(XT, W, acc, ty, tx);
    for (int i = 0; i < 4; i++) {
        int gr = base + ty * 4 + i;
        if (gr < N) {
            #pragma unroll
            for (int j = 0; j < 4; j++) {
                int c = tx * 4 + j;
                xW1p[(size_t)gr * 64 + xw1_pack(c)] = __float2half(acc[i][j] + nn2_b1[c]);
            }
        }
    }
    __syncthreads();
    for (int q = 0; q < 4; q++) ((float4*)W)[t + q * 256] = ((const float4*)nn1_w1)[t + q * 256];
    __syncthreads();
    gemm_tile<68>(XT, W, acc, ty, tx);
    for (int i = 0; i < 4; i++) {
        int gr = base + ty * 4 + i;
        if (gr < N) {
            #pragma unroll
            for (int j = 0; j < 4; j++) {
                int c = tx * 4 + j;
                xA0p[(size_t)gr * 64 + xw1_pack(c)] = __float2half(eps1 * acc[i][j] + nn1_b1[c]);
            }
        }
    }
}

// Edge phase (MFMA): one wave per destination node. LB(256,8) for max TLP on the
// gather-latency chain; epilogue consumes each MFMA D immediately (per-tt) to
// minimize register liveness so 8 waves/SIMD fits without spill.
// L0=1: gathers ea from eid-ordered eaH via csr_eid and MATERIALIZES the
// CSR-ordered copy eaC with coalesced writes. L0=0: reads eaC directly.
template <int L0>
__global__ __launch_bounds__(256, 8) void k_edge(
        const int* __restrict__ rowptr, const int* __restrict__ deg,
        const int* __restrict__ csr_src, const int* __restrict__ csr_eid,
        const __half* __restrict__ eaH, __half* __restrict__ eaC,
        const __half* __restrict__ xW1p,
        const __half* __restrict__ Bfrag,
        __half* __restrict__ Hsum16, int N) {
    int t = threadIdx.x;
    int wave = t >> 6, lane = t & 63;
    int wid = __builtin_amdgcn_readfirstlane(blockIdx.x * 4 + wave);
    if (wid >= N) return;
    int quad = lane >> 4, n = lane & 15;
    f16x8 Bf[4];
    #pragma unroll
    for (int tt = 0; tt < 4; tt++)
        Bf[tt] = *(const f16x8*)(Bfrag + ((size_t)tt * 64 + lane) * 8);
    int beg = __builtin_amdgcn_readfirstlane(rowptr[wid]);
    int end = beg + __builtin_amdgcn_readfirstlane(deg[wid]);
    float acc[4] = {0.f, 0.f, 0.f, 0.f};
    const f32x4v zero = {0.f, 0.f, 0.f, 0.f};
    for (int cbeg = beg; cbeg < end; cbeg += 16) {
        int m = end - cbeg; m = (m < 16) ? m : 16;
        int xs[4];
        #pragma unroll
        for (int r = 0; r < 4; r++) {
            int slot = cbeg + quad * 4 + r;
            slot = (slot < end) ? slot : (end - 1);
            xs[r] = csr_src[slot];
        }
        f16x8 Af;
        #pragma unroll
        for (int j = 0; j < 8; j++) Af[j] = (_Float16)0;
        if (quad < 2) {
            if (L0) {
                int slot = cbeg + ((n < m) ? n : 0);
                int eid = csr_eid[slot];
                f16x8 av = *(const f16x8*)(eaH + (size_t)eid * 16 + quad * 8);
                if (n < m) {
                    Af = av;
                    *(f16x8*)(eaC + (size_t)(cbeg + n) * 16 + quad * 8) = av;
                }
            } else {
                int slot = cbeg + ((n < m) ? n : 0);
                f16x8 av = *(const f16x8*)(eaC + (size_t)slot * 16 + quad * 8);
                if (n < m) Af = av;
            }
        }
        u32x2 xv[4];
        #pragma unroll
        for (int r = 0; r < 4; r++)
            xv[r] = *(const u32x2*)(xW1p + (size_t)xs[r] * 64 + n * 4);
        if (m == 16) {
            #pragma unroll
            for (int tt = 0; tt < 4; tt++) {
                f32x4v D = __builtin_amdgcn_mfma_f32_16x16x32_f16(Af, Bf[tt], zero, 0, 0, 0);
                #pragma unroll
                for (int r = 0; r < 4; r++) {
                    f16x4 xh = __builtin_bit_cast(f16x4, xv[r]);
                    acc[tt] += fmaxf(D[r] + (float)xh[tt], 0.f);
                }
            }
        } else {
            #pragma unroll
            for (int tt = 0; tt < 4; tt++) {
                f32x4v D = __builtin_amdgcn_mfma_f32_16x16x32_f16(Af, Bf[tt], zero, 0, 0, 0);
                #pragma unroll
                for (int r = 0; r < 4; r++) {
                    int e = quad * 4 + r;
                    f16x4 xh = __builtin_bit_cast(f16x4, xv[r]);
                    float z = fmaxf(D[r] + (float)xh[tt], 0.f);
                    acc[tt] += (e < m) ? z : 0.f;
                }
            }
        }
    }
    #pragma unroll
    for (int tt = 0; tt < 4; tt++) {
        acc[tt] += __shfl_xor(acc[tt], 16);
        acc[tt] += __shfl_xor(acc[tt], 32);
    }
    if (quad == 0) {
        #pragma unroll
        for (int tt = 0; tt < 4; tt++)
            Hsum16[(size_t)wid * 64 + tt * 16 + n] = __float2half(acc[tt]);
    }
}

// Node phase (MFMA): 32 nodes/block, 2 waves (finer grid -> less CU tail).
// hL exchange is wave-local (each wave reads only rows it wrote) -> no barrier.
__global__ __launch_bounds__(128) void k_node(
        const __half* __restrict__ Hsum16, const __half* __restrict__ xAp,
        const int* __restrict__ deg, const int* __restrict__ batch,
        const __half* __restrict__ Pf, const float* __restrict__ pb,
        const __half* __restrict__ Qf, const float* __restrict__ qb,
        __half* __restrict__ out1,
        const __half* __restrict__ Rf, const float* __restrict__ rb2,
        __half* __restrict__ out2p,
        float* __restrict__ hpool_l, int N, int has_next) {
    __shared__ _Float16 hL[32 * 72];
    __shared__ float shp[8 * 64];
    int t = threadIdx.x;
    int wave = t >> 6, lane = t & 63;
    int quad = lane >> 4, n = lane & 15;
    int base = blockIdx.x * 32;
    int m0 = base + wave * 16;

    int lastn = base + 31; if (lastn > N - 1) lastn = N - 1;
    int gmin = batch[base];
    int span = batch[lastn] - gmin + 1;
    if (span <= 8) {
        for (int q = t; q < span * 64; q += 128) shp[q] = 0.f;
    }

    int arow = m0 + n; if (arow > N - 1) arow = N - 1;
    f16x8 A0 = *(const f16x8*)(Hsum16 + (size_t)arow * 64 + quad * 8);
    f16x8 A1 = *(const f16x8*)(Hsum16 + (size_t)arow * 64 + 32 + quad * 8);

    f32x4v D[4];
    #pragma unroll
    for (int nt = 0; nt < 4; nt++) {
        f16x8 B0 = *(const f16x8*)(Pf + ((size_t)(nt * 2 + 0) * 64 + lane) * 8);
        f16x8 B1 = *(const f16x8*)(Pf + ((size_t)(nt * 2 + 1) * 64 + lane) * 8);
        f32x4v c0 = {0.f, 0.f, 0.f, 0.f};
        c0 = __builtin_amdgcn_mfma_f32_16x16x32_f16(A0, B0, c0, 0, 0, 0);
        D[nt] = __builtin_amdgcn_mfma_f32_16x16x32_f16(A1, B1, c0, 0, 0, 0);
    }

    float pbv[4];
    #pragma unroll
    for (int nt = 0; nt < 4; nt++) pbv[nt] = pb[nt * 16 + n];

    float h[4][4];   // [r][nt]
    int gidx[4];
    #pragma unroll
    for (int r = 0; r < 4; r++) {
        int node = m0 + quad * 4 + r;
        int nc = (node < N) ? node : (N - 1);
        float dg = 0.f; int g = -1;
        if (node < N) {
            dg = (float)deg[node];
            g = batch[node];
        }
        gidx[r] = g;
        u32x2 xv = *(const u32x2*)(xAp + (size_t)nc * 64 + n * 4);
        f16x4 xh = __builtin_bit_cast(f16x4, xv);
        #pragma unroll
        for (int nt = 0; nt < 4; nt++)
            h[r][nt] = fmaxf(D[nt][r] + (float)xh[nt] + dg * pbv[nt], 0.f);
    }

    if (span <= 8) {
        #pragma unroll
        for (int nt = 0; nt < 4; nt++) {
            int i = 0;
            while (i < 4) {
                if (gidx[i] < 0) { i++; continue; }
                int g = gidx[i];
                float s = h[i][nt];
                int k2 = i + 1;
                while (k2 < 4 && gidx[k2] == g) { s += h[k2][nt]; k2++; }
                atomicAdd(&shp[(g - gmin) * 64 + nt * 16 + n], s);
                i = k2;
            }
        }
        __syncthreads();
        for (int q = t; q < span * 64; q += 128) {
            float v = shp[q];
            if (v != 0.f) atomicAdd(&hpool_l[(gmin + (q >> 6)) * 64 + (q & 63)], v);
        }
    } else {
        #pragma unroll
        for (int nt = 0; nt < 4; nt++) {
            int i = 0;
            while (i < 4) {
                if (gidx[i] < 0) { i++; continue; }
                int g = gidx[i];
                float s = h[i][nt];
                int k2 = i + 1;
                while (k2 < 4 && gidx[k2] == g) { s += h[k2][nt]; k2++; }
                atomicAdd(&hpool_l[g * 64 + nt * 16 + n], s);
                i = k2;
            }
        }
    }

    if (has_next) {
        #pragma unroll
        for (int r = 0; r < 4; r++) {
            int lrow = wave * 16 + quad * 4 + r;
            #pragma unroll
            for (int nt = 0; nt < 4; nt++)
                hL[lrow * 72 + nt * 16 + n] = (_Float16)h[r][nt];
        }
        // no barrier: wave reads only its own 16 rows (lgkmcnt orders within wave)
        int lrowA = wave * 16 + n;
        f16x8 hA0 = *(const f16x8*)(hL + lrowA * 72 + quad * 8);
        f16x8 hA1 = *(const f16x8*)(hL + lrowA * 72 + 32 + quad * 8);
        // GEMM2: h@Q -> out1 (packed f16)
        f32x4v D2[4];
        #pragma unroll
        for (int nt = 0; nt < 4; nt++) {
            f16x8 B0 = *(const f16x8*)(Qf + ((size_t)(nt * 2 + 0) * 64 + lane) * 8);
            f16x8 B1 = *(const f16x8*)(Qf + ((size_t)(nt * 2 + 1) * 64 + lane) * 8);
            f32x4v c0 = {0.f, 0.f, 0.f, 0.f};
            c0 = __builtin_amdgcn_mfma_f32_16x16x32_f16(hA0, B0, c0, 0, 0, 0);
            D2[nt] = __builtin_amdgcn_mfma_f32_16x16x32_f16(hA1, B1, c0, 0, 0, 0);
        }
        float qbv[4];
        #pragma unroll
        for (int nt = 0; nt < 4; nt++) qbv[nt] = qb[nt * 16 + n];
        #pragma unroll
        for (int r = 0; r < 4; r++) {
            int node = m0 + quad * 4 + r;
            if (node < N) {
                H4 o;
                #pragma unroll
                for (int nt = 0; nt < 4; nt++) o.h[nt] = __float2half(D2[nt][r] + qbv[nt]);
                *(H4*)(out1 + (size_t)node * 64 + n * 4) = o;  // packed p = n*4+nt
            }
        }
        // GEMM3: h@Rf' -> out2p (packed f16)
        #pragma unroll
        for (int nt = 0; nt < 4; nt++) {
            f16x8 B0 = *(const f16x8*)(Rf + ((size_t)(nt * 2 + 0) * 64 + lane) * 8);
            f16x8 B1 = *(const f16x8*)(Rf + ((size_t)(nt * 2 + 1) * 64 + lane) * 8);
            f32x4v c0 = {0.f, 0.f, 0.f, 0.f};
            c0 = __builtin_amdgcn_mfma_f32_16x16x32_f16(hA0, B0, c0, 0, 0, 0);
            D2[nt] = __builtin_amdgcn_mfma_f32_16x16x32_f16(hA1, B1, c0, 0, 0, 0);
        }
        float rbv[4];
        #pragma unroll
        for (int nt = 0; nt < 4; nt++) rbv[nt] = rb2[nt * 16 + n];
        #pragma unroll
        for (int r = 0; r < 4; r++) {
            int node = m0 + quad * 4 + r;
            if (node < N) {
                f16x4 o;
                #pragma unroll
                for (int nt = 0; nt < 4; nt++) o[nt] = (_Float16)(D2[nt][r] + rbv[nt]);
                *(f16x4*)(out2p + (size_t)node * 64 + n * 4) = o;
            }
        }
    }
}

// fused readout: 4 groups per block amortizes the F1 stream (210 -> 52 MB).
#define GPB 4
__global__ void k_pool_final(const float* __restrict__ hpool, const int* __restrict__ cnt,
                             const float* __restrict__ nn1_w2, const float* __restrict__ nn1_b2,
                             const float* __restrict__ F1, const float* __restrict__ fb1,
                             const float* __restrict__ F2, const float* __restrict__ fb2,
                             float* __restrict__ out, int G) {
    int g0 = blockIdx.x * GPB;
    int c = threadIdx.x; // 320
    int lane = c & 63, w = c >> 6;
    int l = c >> 6, cc = c & 63;
    const float* B = nn1_w2 + l * 4096;
    __shared__ float sh1[GPB][320];
    __shared__ float ws[GPB][8];
    float bias = nn1_b2[l * 64 + cc];
    #pragma unroll
    for (int gi = 0; gi < GPB; gi++) {
        int g = g0 + gi;
        if (g >= G) break;
        const float* hp = hpool + ((size_t)l * G + g) * 64;
        float s = (float)cnt[g] * bias;
        for (int k = 0; k < 64; k++) s += hp[k] * B[k * 64 + cc];
        sh1[gi][c] = s;
    }
    __syncthreads();
    float acc[GPB];
    #pragma unroll
    for (int gi = 0; gi < GPB; gi++) acc[gi] = fb1[c];
    for (int k = 0; k < 320; k++) {
        float wv = F1[k * 320 + c];
        #pragma unroll
        for (int gi = 0; gi < GPB; gi++) acc[gi] += sh1[gi][k] * wv;
    }
    float f2 = F2[c];
    #pragma unroll
    for (int gi = 0; gi < GPB; gi++) {
        float v = fmaxf(acc[gi], 0.f) * f2;
        v += __shfl_xor(v, 32);
        v += __shfl_xor(v, 16);
        v += __shfl_xor(v, 8);
        v += __shfl_xor(v, 4);
        v += __shfl_xor(v, 2);
        v += __shfl_xor(v, 1);
        if (lane == 0) ws[gi][w] = v;
    }
    __syncthreads();
    if (c < GPB) {
        int g = g0 + c;
        if (g < G) {
            float y = fb2[0];
            #pragma unroll
            for (int k = 0; k < 5; k++) y += ws[c][k];
            out[g] = y;
        }
    }
}

extern "C" void kernel_launch(void* const* d_in, const int* in_sizes, int n_in,
                              void* d_out, int out_size, void* d_ws, size_t ws_size,
                              hipStream_t stream) {
    const float* x        = (const float*)d_in[0];
    const int*   ei       = (const int*)d_in[1];
    const float* edge_attr= (const float*)d_in[2];
    const int*   batch    = (const int*)d_in[3];
    const float* nn2_w1   = (const float*)d_in[4];
    const float* nn2_b1   = (const float*)d_in[5];
    const float* nn2_w2   = (const float*)d_in[6];
    const float* nn2_b2   = (const float*)d_in[7];
    const float* nn1_w1   = (const float*)d_in[8];
    const float* nn1_b1   = (const float*)d_in[9];
    const float* nn1_w2   = (const float*)d_in[10];
    const float* nn1_b2   = (const float*)d_in[11];
    const float* fin_w1   = (const float*)d_in[12];
    const float* fin_b1   = (const float*)d_in[13];
    const float* fin_w2   = (const float*)d_in[14];
    const float* fin_b2   = (const float*)d_in[15];
    const float* eps      = (const float*)d_in[16];

    int N = in_sizes[0] / 64;
    int E = in_sizes[1] / 2;
    int G = out_size;

    char* p = (char*)d_ws;
    auto alloc = [&](size_t bytes) -> char* {
        char* r = p;
        p += (bytes + 255) & ~(size_t)255;
        return r;
    };
    // zero-init region: deg, cnt, cursor, hpool — contiguous, one memset.
    char*   zbase   = p;
    int*    deg     = (int*)alloc((size_t)N * 4);
    int*    cnt     = (int*)alloc((size_t)G * 4);
    int*    cursor  = (int*)alloc(256);
    float*  hpool   = (float*)alloc((size_t)NLAYERS * G * 64 * 4);
    size_t  zlen    = (size_t)(p - zbase);

    int*    rowptr  = (int*)alloc((size_t)N * 4);
    int*    rank    = (int*)alloc((size_t)E * 4);
    int*    csr_src = (int*)alloc((size_t)E * 4 + 256);
    int*    csr_eid = (int*)alloc((size_t)E * 4 + 256);
    __half* eaH     = (__half*)alloc((size_t)E * 16 * 2 + 1024);
    __half* eaC     = (__half*)alloc((size_t)E * 16 * 2 + 1024);
    __half* xW1p    = (__half*)alloc((size_t)N * 64 * 2);
    __half* xA0p    = (__half*)alloc((size_t)N * 64 * 2);
    __half* xA1p    = (__half*)alloc((size_t)N * 64 * 2);
    __half* Hsum16  = (__half*)alloc((size_t)N * 64 * 2);
    __half* Ff      = (__half*)alloc(13 * 4096 * 2);
    float*  pb      = (float*)alloc(5 * 64 * 4);
    float*  qb      = (float*)alloc(4 * 64 * 4);
    float*  rb      = (float*)alloc(4 * 64 * 4);
    __half* Bfrag   = (__half*)alloc(5 * 4 * 64 * 8 * 2);

    hipMemsetAsync(zbase, 0, zlen, stream);

    int Pblk = (N + 255) / 256;
    int nb64 = (N + 63) / 64;
    int nb32 = (N + 31) / 32;
    int EB = (E + 255) / 256;
    k_rank<<<EB, 256, 0, stream>>>(ei, E, deg, rank, batch, N, cnt, edge_attr, eaH);
    k_prep<<<18 + nb64, 256, 0, stream>>>(x, nn2_w1, nn2_b1, nn2_w2, nn2_b2,
                                          nn1_w1, nn1_b1, nn1_w2, nn1_b2, eps,
                                          Ff, pb, qb, rb, Bfrag, xW1p, xA0p, N);
    k_off<<<Pblk, 256, 0, stream>>>(deg, N, cursor, rowptr);
    k_scatter_sd<<<EB, 256, 0, stream>>>(ei, rank, rowptr, E, csr_src, csr_eid);

    __half* xA_cur = xA0p;
    __half* xA_nxt = xA1p;
    int eblocks = (N + 3) / 4;
    for (int l = 0; l < NLAYERS; l++) {
        int has_next = (l < NLAYERS - 1) ? 1 : 0;
        if (l == 0)
            k_edge<1><<<eblocks, 256, 0, stream>>>(rowptr, deg, csr_src, csr_eid, eaH, eaC, xW1p,
                                                   Bfrag + (size_t)l * 2048, Hsum16, N);
        else
            k_edge<0><<<eblocks, 256, 0, stream>>>(rowptr, deg, csr_src, csr_eid, eaH, eaC, xW1p,
                                                   Bfrag + (size_t)l * 2048, Hsum16, N);
        k_node<<<nb32, 128, 0, stream>>>(Hsum16, xA_cur, deg, batch,
                                         Ff + (size_t)l * 4096, pb + l * 64,
                                         Ff + (size_t)(5 + (has_next ? l : 0)) * 4096, qb + (has_next ? l : 0) * 64, xW1p,
                                         Ff + (size_t)(9 + (has_next ? l : 0)) * 4096, rb + (has_next ? l : 0) * 64, xA_nxt,
                                         hpool + (size_t)l * G * 64, N, has_next);
        __half* tmp = xA_cur; xA_cur = xA_nxt; xA_nxt = tmp;
    }

    k_pool_final<<<(G + GPB - 1) / GPB, 320, 0, stream>>>(hpool, cnt, nn1_w2, nn1_b2,
                                        fin_w1, fin_b1, fin_w2, fin_b2, (float*)d_out, G);
}